// Round 10
// baseline (279.260 us; speedup 1.0000x reference)
//
#include <hip/hip_runtime.h>
#include <hip/hip_bf16.h>
#include <math.h>

// ---------------------------------------------------------------------------
// GNN link predictor: 2-layer GraphSAGE (mean agg) + dot-product + sigmoid.
//  - transform-then-aggregate (mean is linear) -> aggregate in 64-dim space
//  - GEMMs on MFMA (16x16x32 bf16, fp32 accum), W-frags register-resident
//  - R10 CSR: single-pass ragged scatter. Edges land in per-(bucket,block)
//    32-int cells (one 128B line each, LDS cursors, ZERO global atomics /
//    scans — R6/R7 showed returning device atomics are a 24.6G/s HW wall);
//    k_bfinal does a purely bucket-local counting sort into fixed-capacity
//    segments (offs[] are ragged pointers — nothing needs global contiguity).
//  - R10: root path Q stored bf16 (halves gemm-out + agg-in root traffic).
//  - gathers: uint4 (8 lanes x 16B = one 128B row), 8 nodes/wave.
// ---------------------------------------------------------------------------

#define HID 64
#define G_BLK 256    // blocks in scatter pass
#define BSH 7        // bucket = 128 nodes
#define BNODES 128
#define BCAP 32      // ints per (bucket,block) cell = one 128B line
#define CAPK 2560    // per-bucket sorted capacity (mean 2046, +11 sigma)
#define NB_MAX 1024  // max buckets

typedef __attribute__((ext_vector_type(8))) short short8;   // 8 bf16 (4 VGPR)
typedef __attribute__((ext_vector_type(4))) float floatx4;  // MFMA acc

__device__ __forceinline__ unsigned short f2bf(float f) {
    union { float f; unsigned u; } v; v.f = f;
    unsigned r = v.u + 0x7FFF + ((v.u >> 16) & 1);  // round-to-nearest-even
    return (unsigned short)(r >> 16);
}
__device__ __forceinline__ float bf2f(unsigned short u) {
    union { unsigned u; float f; } v; v.u = ((unsigned)u) << 16;
    return v.f;
}
__device__ __forceinline__ unsigned pack_bf2(float a, float b) {
    union { __hip_bfloat162 h; unsigned u; } cv;
    cv.h = __float22bfloat162_rn(make_float2(a, b));  // v_cvt_pk_bf16_f32
    return cv.u;
}
__device__ __forceinline__ void acc8(float* a, uint4 u) {
    a[0] += bf2f((unsigned short)u.x); a[1] += bf2f((unsigned short)(u.x >> 16));
    a[2] += bf2f((unsigned short)u.y); a[3] += bf2f((unsigned short)(u.y >> 16));
    a[4] += bf2f((unsigned short)u.z); a[5] += bf2f((unsigned short)(u.z >> 16));
    a[6] += bf2f((unsigned short)u.w); a[7] += bf2f((unsigned short)(u.w >> 16));
}

// ---------------- CSR build: single-pass ragged scatter ----------------

// Each block b scatters its edge chunk into cells ebuf[(k*G_BLK+b)*BCAP + slot]
// via LDS cursors; writes cnt[k*G_BLK+b]. payload = (dst&127)<<25... (7 bits<<24)|src.
__global__ __launch_bounds__(256)
void k_scat1p(const int* __restrict__ esrc, const int* __restrict__ edst,
              int* __restrict__ ebuf, int* __restrict__ cnt,
              int E, int NB, int CH) {
    __shared__ int lcur[NB_MAX];
    const int b = blockIdx.x;
    for (int k = threadIdx.x; k < NB; k += 256) lcur[k] = 0;
    __syncthreads();
    const int e0 = b * CH, e1 = min(E, e0 + CH);
    for (int e = e0 + threadIdx.x; e < e1; e += 256) {
        int d = edst[e];
        int k = d >> BSH;
        int slot = atomicAdd(&lcur[k], 1);  // LDS atomic
        if (slot < BCAP)
            ebuf[(((size_t)k * G_BLK + b) << 5) + slot] =
                ((d & (BNODES - 1)) << 24) | esrc[e];
    }
    __syncthreads();
    for (int k = threadIdx.x; k < NB; k += 256)
        cnt[(size_t)k * G_BLK + b] = min(lcur[k], BCAP);
}

// Per-bucket local counting sort: cache edges in LDS, hist+scan over the 128
// local nodes, write sorted into the bucket's private segment [k*CAPK, ...).
__global__ __launch_bounds__(256)
void k_bfinal(const int* __restrict__ ebuf, const int* __restrict__ cnt,
              int* __restrict__ sorted, int* __restrict__ deg,
              int* __restrict__ offs, int N) {
    __shared__ int epk[CAPK];
    __shared__ int lcnt[G_BLK], pref[G_BLK], sc[256];
    __shared__ int h[BNODES], loc[BNODES], cur[BNODES];
    const int k = blockIdx.x;
    const int t = threadIdx.x;
    // counts + block-local prefix over the 256 cells
    int v = cnt[(size_t)k * G_BLK + t];
    lcnt[t] = v;
    sc[t] = v;
    __syncthreads();
    for (int off = 1; off < 256; off <<= 1) {
        int x = (t >= off) ? sc[t - off] : 0;
        __syncthreads();
        sc[t] += x;
        __syncthreads();
    }
    pref[t] = sc[t] - v;
    if (t < BNODES) h[t] = 0;
    __syncthreads();
    const int total = min(sc[255], CAPK);
    // compact cells into LDS (wave wv covers cells [wv*64, wv*64+64))
    {
        const int wv = t >> 6, lane = t & 63;
        for (int b = wv * 64; b < wv * 64 + 64; ++b) {
            int n = lcnt[b];
            if (lane < n) {
                int p = pref[b] + lane;
                if (p < CAPK)
                    epk[p] = ebuf[(((size_t)k * G_BLK + b) << 5) + lane];
            }
        }
    }
    __syncthreads();
    for (int i = t; i < total; i += 256)
        atomicAdd(&h[(epk[i] >> 24) & (BNODES - 1)], 1);  // LDS atomic
    __syncthreads();
    // scan h over 128 nodes (use sc, zero-padded)
    int hv = (t < BNODES) ? h[t] : 0;
    sc[t] = hv;
    __syncthreads();
    for (int off = 1; off < 256; off <<= 1) {
        int x = (t >= off) ? sc[t - off] : 0;
        __syncthreads();
        sc[t] += x;
        __syncthreads();
    }
    if (t < BNODES) { loc[t] = sc[t] - hv; cur[t] = sc[t] - hv; }
    __syncthreads();
    for (int i = t; i < total; i += 256) {
        int pk = epk[i];
        int row = (pk >> 24) & (BNODES - 1);
        int r = atomicAdd(&cur[row], 1);  // LDS atomic
        sorted[(size_t)k * CAPK + r] = pk & 0xFFFFFF;
    }
    if (t < BNODES) {
        int node = (k << BSH) + t;
        if (node < N) {
            deg[node] = hv;
            offs[node] = k * CAPK + loc[t];
        }
    }
}

// ---------------- W cast: Wcb1 = bf16([Wl1;Wr1]) 128x128, Wcb2 = bf16([Wl2;Wr2]) 128x64

__global__ __launch_bounds__(256)
void k_castw(const float* __restrict__ Wl1, const float* __restrict__ Wr1,
             const float* __restrict__ Wl2, const float* __restrict__ Wr2,
             unsigned short* __restrict__ Wcb1, unsigned short* __restrict__ Wcb2) {
    int i = blockIdx.x * 256 + threadIdx.x;
    if (i < 16384) {
        Wcb1[i] = f2bf(i < 8192 ? Wl1[i] : Wr1[i - 8192]);
    } else if (i < 24576) {
        int j = i - 16384;
        Wcb2[j] = f2bf(j < 4096 ? Wl2[j] : Wr2[j - 4096]);
    }
}

// ---------------- MFMA dual GEMM: [P|Q] = A @ [Wl;Wr]^T ----------------
// Wave computes 16 rows x 64 cols (half=0 -> P, half=1 -> Q), both bf16 out.
// B-frags held in registers across a grid-stride row-tile loop.
// A is f32 (layer 1, cvt in-flight) or bf16 (layer 2).

template <int K, bool AF32>
__global__ __launch_bounds__(256, 2)
void gemm_mfma(const void* __restrict__ Xv, const unsigned short* __restrict__ Wcb,
               unsigned short* __restrict__ Pb, unsigned short* __restrict__ Qb,
               int N) {
    const int lane = threadIdx.x & 63;
    const int m = lane & 15;        // row (A) / col (B) within tile
    const int q = lane >> 4;        // k-quad
    const int gw = blockIdx.x * 4 + (threadIdx.x >> 6);
    const int half = gw & 1;        // 0 -> P, 1 -> Q
    constexpr int KB = K / 32;

    short8 bf[KB][4];
#pragma unroll
    for (int kb = 0; kb < KB; ++kb)
#pragma unroll
        for (int ct = 0; ct < 4; ++ct) {
            int c = half * 64 + ct * 16 + m;
            bf[kb][ct] = *(const short8*)(Wcb + (size_t)c * K + kb * 32 + q * 8);
        }

    unsigned short* dstp = half ? Qb : Pb;
    const int ntiles = (N + 15) >> 4;
    const int stride = gridDim.x * 2;  // waves per half
    for (int t = gw >> 1; t < ntiles; t += stride) {
        const int r0 = t << 4;
        int rr = r0 + m;
        if (rr >= N) rr = N - 1;
        floatx4 acc[4];
#pragma unroll
        for (int ct = 0; ct < 4; ++ct) acc[ct] = (floatx4){0.f, 0.f, 0.f, 0.f};

#pragma unroll
        for (int kb = 0; kb < KB; ++kb) {
            short8 a;
            if (AF32) {
                const float* xp = (const float*)Xv + (size_t)rr * K + kb * 32 + q * 8;
                float4 x0 = *(const float4*)xp;
                float4 x1 = *(const float4*)(xp + 4);
                union { unsigned u[4]; short8 s; } cv;
                cv.u[0] = pack_bf2(x0.x, x0.y);
                cv.u[1] = pack_bf2(x0.z, x0.w);
                cv.u[2] = pack_bf2(x1.x, x1.y);
                cv.u[3] = pack_bf2(x1.z, x1.w);
                a = cv.s;
            } else {
                a = *(const short8*)((const unsigned short*)Xv + (size_t)rr * K + kb * 32 + q * 8);
            }
#pragma unroll
            for (int ct = 0; ct < 4; ++ct)
                acc[ct] = __builtin_amdgcn_mfma_f32_16x16x32_bf16(a, bf[kb][ct], acc[ct], 0, 0, 0);
        }

        // C/D: col = ct*16 + m, row = r0 + q*4 + i
#pragma unroll
        for (int i = 0; i < 4; ++i) {
            int row = r0 + q * 4 + i;
            if (row < N) {
#pragma unroll
                for (int ct = 0; ct < 4; ++ct)
                    dstp[(size_t)row * HID + ct * 16 + m] = f2bf(acc[ct][i]);
            }
        }
    }
}

// ------- aggregation: H = relu(mean_{s in N(n)} P[s] + bias + Q[n]) -------
// 8 nodes per wave (8 lanes/node), lane = uint4 = 8 bf16 channels.
// Q (root path) is bf16: two uint2 reads per lane.

__global__ __launch_bounds__(256)
void k_agg(const uint4* __restrict__ P8, const uint2* __restrict__ Qb4,
           const float4* __restrict__ bias4, const int* __restrict__ offs,
           const int* __restrict__ deg, const int* __restrict__ sorted,
           uint4* __restrict__ H8, int N) {
    int node = blockIdx.x * 32 + (threadIdx.x >> 3);
    int c8 = threadIdx.x & 7;
    if (node >= N) return;
    int off = offs[node];
    int c = deg[node];
    float a[8];
#pragma unroll
    for (int j = 0; j < 8; ++j) a[j] = 0.f;
    int i = 0;
    for (; i + 1 < c; i += 2) {
        int s0 = sorted[off + i];
        int s1 = sorted[off + i + 1];
        uint4 u0 = P8[(size_t)s0 * 8 + c8];
        uint4 u1 = P8[(size_t)s1 * 8 + c8];
        acc8(a, u0);
        acc8(a, u1);
    }
    if (i < c) acc8(a, P8[(size_t)sorted[off + i] * 8 + c8]);

    float inv = 1.0f / (float)(c > 0 ? c : 1);
    float4 b0 = bias4[c8 * 2], b1 = bias4[c8 * 2 + 1];
    uint2 q0 = Qb4[(size_t)node * 16 + c8 * 2];
    uint2 q1 = Qb4[(size_t)node * 16 + c8 * 2 + 1];
    float v0 = a[0] * inv + b0.x + bf2f((unsigned short)q0.x);
    float v1 = a[1] * inv + b0.y + bf2f((unsigned short)(q0.x >> 16));
    float v2 = a[2] * inv + b0.z + bf2f((unsigned short)q0.y);
    float v3 = a[3] * inv + b0.w + bf2f((unsigned short)(q0.y >> 16));
    float v4 = a[4] * inv + b1.x + bf2f((unsigned short)q1.x);
    float v5 = a[5] * inv + b1.y + bf2f((unsigned short)(q1.x >> 16));
    float v6 = a[6] * inv + b1.z + bf2f((unsigned short)q1.y);
    float v7 = a[7] * inv + b1.w + bf2f((unsigned short)(q1.y >> 16));
    v0 = fmaxf(v0, 0.f); v1 = fmaxf(v1, 0.f); v2 = fmaxf(v2, 0.f); v3 = fmaxf(v3, 0.f);
    v4 = fmaxf(v4, 0.f); v5 = fmaxf(v5, 0.f); v6 = fmaxf(v6, 0.f); v7 = fmaxf(v7, 0.f);
    uint4 hp;
    hp.x = (unsigned)f2bf(v0) | ((unsigned)f2bf(v1) << 16);
    hp.y = (unsigned)f2bf(v2) | ((unsigned)f2bf(v3) << 16);
    hp.z = (unsigned)f2bf(v4) | ((unsigned)f2bf(v5) << 16);
    hp.w = (unsigned)f2bf(v6) | ((unsigned)f2bf(v7) << 16);
    H8[(size_t)node * 8 + c8] = hp;
}

// ---------------- query: out[q] = sigmoid(sum_c Z[s][c]*Z[d][c]) ----------------
// 8 queries per wave (8 lanes each), uint4 bf16x8 loads.

__global__ __launch_bounds__(256)
void k_query(const uint4* __restrict__ Z8, const int* __restrict__ src,
             const int* __restrict__ dst, float* __restrict__ out, int Q) {
    int qi = blockIdx.x * 32 + (threadIdx.x >> 3);
    int c8 = threadIdx.x & 7;
    if (qi >= Q) return;
    int s = src[qi];
    int d = dst[qi];
    uint4 us = Z8[(size_t)s * 8 + c8];
    uint4 ud = Z8[(size_t)d * 8 + c8];
    float v =
        bf2f((unsigned short)us.x) * bf2f((unsigned short)ud.x) +
        bf2f((unsigned short)(us.x >> 16)) * bf2f((unsigned short)(ud.x >> 16)) +
        bf2f((unsigned short)us.y) * bf2f((unsigned short)ud.y) +
        bf2f((unsigned short)(us.y >> 16)) * bf2f((unsigned short)(ud.y >> 16)) +
        bf2f((unsigned short)us.z) * bf2f((unsigned short)ud.z) +
        bf2f((unsigned short)(us.z >> 16)) * bf2f((unsigned short)(ud.z >> 16)) +
        bf2f((unsigned short)us.w) * bf2f((unsigned short)ud.w) +
        bf2f((unsigned short)(us.w >> 16)) * bf2f((unsigned short)(ud.w >> 16));
#pragma unroll
    for (int mres = 4; mres > 0; mres >>= 1) v += __shfl_xor(v, mres, 64);
    if (c8 == 0) out[qi] = 1.0f / (1.0f + __expf(-v));
}

// ---------------- launch ----------------

extern "C" void kernel_launch(void* const* d_in, const int* in_sizes, int n_in,
                              void* d_out, int out_size, void* d_ws, size_t ws_size,
                              hipStream_t stream) {
    const float* x    = (const float*)d_in[0];
    const int*   ei   = (const int*)d_in[1];
    const int*   qsrc = (const int*)d_in[2];
    const int*   qdst = (const int*)d_in[3];
    const float* Wl1  = (const float*)d_in[4];
    const float* bl1  = (const float*)d_in[5];
    const float* Wr1  = (const float*)d_in[6];
    const float* Wl2  = (const float*)d_in[7];
    const float* bl2  = (const float*)d_in[8];
    const float* Wr2  = (const float*)d_in[9];
    float* out = (float*)d_out;

    const int N = in_sizes[0] / 128;  // IN_CH = 128
    const int E = in_sizes[1] / 2;
    const int Q = in_sizes[2];

    const int* esrc = ei;
    const int* edst = ei + E;

    const int NB = (N + BNODES - 1) >> BSH;   // buckets of 128 nodes (<= NB_MAX)
    const int CH = (E + G_BLK - 1) / G_BLK;   // edges per scatter block

    // workspace layout (no aliasing; ws is 256 MiB)
    unsigned short* Pb = (unsigned short*)d_ws;         // N x 64 bf16 messages
    unsigned short* Qb = Pb + (size_t)N * HID;          // N x 64 bf16 root
    unsigned short* Hb = Qb + (size_t)N * HID;          // N x 64 bf16 h
    unsigned short* Zb = Hb + (size_t)N * HID;          // N x 64 bf16 z
    int* deg_c  = (int*)(Zb + (size_t)N * HID);         // N
    int* offs   = deg_c + N;                            // N
    int* cnt    = offs + N;                             // NB*G_BLK
    int* ebuf   = cnt + (size_t)NB * G_BLK;             // NB*G_BLK*BCAP
    int* sorted = ebuf + (size_t)NB * G_BLK * BCAP;     // NB*CAPK
    unsigned short* Wcb1 = (unsigned short*)(sorted + (size_t)NB * CAPK);
    unsigned short* Wcb2 = Wcb1 + 16384;

    const int gG = 640;              // grid-stride MFMA gemm
    const int gA = (N + 31) / 32;    // 8 nodes/wave, 4 waves/block
    const int gQ = (Q + 31) / 32;

    // CSR build: 2 kernels, zero global atomics, zero scans
    k_castw<<<96, 256, 0, stream>>>(Wl1, Wr1, Wl2, Wr2, Wcb1, Wcb2);
    k_scat1p<<<G_BLK, 256, 0, stream>>>(esrc, edst, ebuf, cnt, E, NB, CH);
    k_bfinal<<<NB, 256, 0, stream>>>(ebuf, cnt, sorted, deg_c, offs, N);

    // layer 1: Pb = bf16(x@Wl1^T), Qb = bf16(x@Wr1^T); Hb = bf16(relu(mean+b+Qb))
    gemm_mfma<128, true><<<gG, 256, 0, stream>>>(x, Wcb1, Pb, Qb, N);
    k_agg<<<gA, 256, 0, stream>>>((const uint4*)Pb, (const uint2*)Qb,
                                  (const float4*)bl1, offs, deg_c, sorted,
                                  (uint4*)Hb, N);

    // layer 2: Pb = bf16(Hb@Wl2^T), Qb = bf16(Hb@Wr2^T); Zb = bf16(relu(mean+b+Qb))
    gemm_mfma<64, false><<<gG, 256, 0, stream>>>(Hb, Wcb2, Pb, Qb, N);
    k_agg<<<gA, 256, 0, stream>>>((const uint4*)Pb, (const uint2*)Qb,
                                  (const float4*)bl2, offs, deg_c, sorted,
                                  (uint4*)Zb, N);

    // queries
    k_query<<<gQ, 256, 0, stream>>>((const uint4*)Zb, qsrc, qdst, out, Q);
}

// Round 11
// 264.064 us; speedup vs baseline: 1.0575x; 1.0575x over previous
//
#include <hip/hip_runtime.h>
#include <hip/hip_bf16.h>
#include <math.h>

// ---------------------------------------------------------------------------
// GNN link predictor: 2-layer GraphSAGE (mean agg) + dot-product + sigmoid.
//  - transform-then-aggregate (mean is linear) -> aggregate in 64-dim space
//  - GEMMs on MFMA (16x16x32 bf16, fp32 accum), W read f32 + packed to
//    register-resident bf16 B-frags (castw kernel folded in, R11)
//  - CSR build: 2-level LDS counting sort (bucket = dst>>8), ZERO global
//    atomics (R6/R7: returning device atomics = 24.6G/s HW wall).
//    R11: bhist/bscatter at G_BLK=1024 (4 blk/CU) — R10 showed these
//    passes are latency-bound (scat1p at 256 blocks: 8.8% occ, 46us);
//    wave count is the lever.
//  - root path Q stored bf16 (R10 win, kept)
//  - gathers: uint4 (8 lanes x 16B = one 128B row), 8 nodes/wave
// ---------------------------------------------------------------------------

#define HID 64
#define G_BLK 1024  // blocks in bucket passes A/C (4 blocks/CU)
#define NB_MAX 512  // max buckets of 256 nodes (N <= 131072)

typedef __attribute__((ext_vector_type(8))) short short8;   // 8 bf16 (4 VGPR)
typedef __attribute__((ext_vector_type(4))) float floatx4;  // MFMA acc

__device__ __forceinline__ unsigned short f2bf(float f) {
    union { float f; unsigned u; } v; v.f = f;
    unsigned r = v.u + 0x7FFF + ((v.u >> 16) & 1);  // round-to-nearest-even
    return (unsigned short)(r >> 16);
}
__device__ __forceinline__ float bf2f(unsigned short u) {
    union { unsigned u; float f; } v; v.u = ((unsigned)u) << 16;
    return v.f;
}
__device__ __forceinline__ unsigned pack_bf2(float a, float b) {
    union { __hip_bfloat162 h; unsigned u; } cv;
    cv.h = __float22bfloat162_rn(make_float2(a, b));  // v_cvt_pk_bf16_f32
    return cv.u;
}
__device__ __forceinline__ void acc8(float* a, uint4 u) {
    a[0] += bf2f((unsigned short)u.x); a[1] += bf2f((unsigned short)(u.x >> 16));
    a[2] += bf2f((unsigned short)u.y); a[3] += bf2f((unsigned short)(u.y >> 16));
    a[4] += bf2f((unsigned short)u.z); a[5] += bf2f((unsigned short)(u.z >> 16));
    a[6] += bf2f((unsigned short)u.w); a[7] += bf2f((unsigned short)(u.w >> 16));
}

// ---------------- CSR build: 2-level LDS counting sort ----------------

// Pass A: per-block LDS histogram over buckets (dst>>8). cnt[k*G_BLK + b].
__global__ __launch_bounds__(256)
void k_bhist(const int* __restrict__ edst, int* __restrict__ cnt,
             int E, int NB, int CH) {
    __shared__ int lh[NB_MAX];
    const int b = blockIdx.x;
    for (int i = threadIdx.x; i < NB; i += 256) lh[i] = 0;
    __syncthreads();
    const int e0 = b * CH;
    const int e1 = min(E, e0 + CH);
    for (int e = e0 + threadIdx.x; e < e1; e += 256)
        atomicAdd(&lh[edst[e] >> 8], 1);  // LDS atomic
    __syncthreads();
    for (int k = threadIdx.x; k < NB; k += 256)
        cnt[(size_t)k * G_BLK + b] = lh[k];
}

// Pass B1: per-bucket exclusive scan over the G_BLK block counts (wave/bucket).
__global__ __launch_bounds__(256)
void k_bscan1(int* __restrict__ cnt, int* __restrict__ total, int NB) {
    int k = blockIdx.x * 4 + (threadIdx.x >> 6);
    int lane = threadIdx.x & 63;
    if (k >= NB) return;
    int* row = cnt + (size_t)k * G_BLK;
    const int base = lane * 16;  // 16 consecutive blocks per lane
    int v[16];
#pragma unroll
    for (int j = 0; j < 16; ++j) v[j] = row[base + j];
    int s = 0;
#pragma unroll
    for (int j = 0; j < 16; ++j) s += v[j];
    int inc = s;
#pragma unroll
    for (int off = 1; off < 64; off <<= 1) {
        int o = __shfl_up(inc, off, 64);
        if (lane >= off) inc += o;
    }
    int run = inc - s;  // exclusive prefix of this lane's chunk
#pragma unroll
    for (int j = 0; j < 16; ++j) { int t = v[j]; row[base + j] = run; run += t; }
    if (lane == 63) total[k] = run;
}

// Pass B2: exclusive scan of bucket totals -> base. One block, 512 threads.
__global__ __launch_bounds__(512)
void k_bscan2(const int* __restrict__ total, int* __restrict__ base, int NB) {
    __shared__ int lds[512];
    int t = threadIdx.x;
    int v = (t < NB) ? total[t] : 0;
    lds[t] = v;
    __syncthreads();
    for (int off = 1; off < 512; off <<= 1) {
        int x = (t >= off) ? lds[t - off] : 0;
        __syncthreads();
        lds[t] += x;
        __syncthreads();
    }
    if (t < NB) base[t] = lds[t] - v;
}

// Pass C: scatter edges into bucket segments via LDS cursors (no global atomics).
// payload = (dst&255)<<24 | src  (src < 2^24).
__global__ __launch_bounds__(256)
void k_bscatter(const int* __restrict__ esrc, const int* __restrict__ edst,
                const int* __restrict__ cnt, const int* __restrict__ base,
                int* __restrict__ ebuf, int E, int NB, int CH) {
    __shared__ int cur[NB_MAX];
    const int b = blockIdx.x;
    for (int k = threadIdx.x; k < NB; k += 256)
        cur[k] = base[k] + cnt[(size_t)k * G_BLK + b];
    __syncthreads();
    const int e0 = b * CH;
    const int e1 = min(E, e0 + CH);
    for (int e = e0 + threadIdx.x; e < e1; e += 256) {
        int d = edst[e];
        int slot = atomicAdd(&cur[d >> 8], 1);  // LDS atomic
        ebuf[slot] = ((d & 255) << 24) | esrc[e];
    }
}

// Pass D: per-bucket local counting sort -> sorted[], deg[], offs[].
__global__ __launch_bounds__(256)
void k_bfinal(const int* __restrict__ ebuf, const int* __restrict__ total,
              const int* __restrict__ base, int* __restrict__ sorted,
              int* __restrict__ deg, int* __restrict__ offs, int N) {
    __shared__ int h[256], loc[256], cur[256], sc[256];
    const int k = blockIdx.x;
    const int t = threadIdx.x;
    const int nk = total[k];
    const int bs = base[k];
    h[t] = 0;
    __syncthreads();
    for (int i = bs + t; i < bs + nk; i += 256)
        atomicAdd(&h[(ebuf[i] >> 24) & 255], 1);
    __syncthreads();
    int v = h[t];
    sc[t] = v;
    __syncthreads();
    for (int off = 1; off < 256; off <<= 1) {
        int x = (t >= off) ? sc[t - off] : 0;
        __syncthreads();
        sc[t] += x;
        __syncthreads();
    }
    loc[t] = sc[t] - v;
    cur[t] = sc[t] - v;
    __syncthreads();
    for (int i = bs + t; i < bs + nk; i += 256) {
        int pk = ebuf[i];
        int j = (pk >> 24) & 255;
        int r = atomicAdd(&cur[j], 1);  // LDS atomic
        sorted[bs + r] = pk & 0xFFFFFF;
    }
    int node = (k << 8) + t;
    if (node < N) {
        deg[node] = v;
        offs[node] = bs + loc[t];
    }
}

// ---------------- MFMA dual GEMM: [P|Q] = A @ [Wl;Wr]^T ----------------
// Wave computes 16 rows x 64 cols (half=0 -> P, half=1 -> Q), both bf16 out.
// B-frags: read f32 W rows once per wave, pack to bf16 registers (no castw
// kernel). A is f32 (layer 1, cvt in-flight) or bf16 (layer 2).

template <int K, bool AF32>
__global__ __launch_bounds__(256, 2)
void gemm_mfma(const void* __restrict__ Xv, const float* __restrict__ Wl,
               const float* __restrict__ Wr, unsigned short* __restrict__ Pb,
               unsigned short* __restrict__ Qb, int N) {
    const int lane = threadIdx.x & 63;
    const int m = lane & 15;        // row (A) / col (B) within tile
    const int q = lane >> 4;        // k-quad
    const int gw = blockIdx.x * 4 + (threadIdx.x >> 6);
    const int half = gw & 1;        // 0 -> P, 1 -> Q
    constexpr int KB = K / 32;

    const float* Wh = half ? Wr : Wl;
    short8 bf[KB][4];
#pragma unroll
    for (int kb = 0; kb < KB; ++kb)
#pragma unroll
        for (int ct = 0; ct < 4; ++ct) {
            int c = ct * 16 + m;
            const float* wp = Wh + (size_t)c * K + kb * 32 + q * 8;
            float4 w0 = *(const float4*)wp;
            float4 w1 = *(const float4*)(wp + 4);
            union { unsigned u[4]; short8 s; } cv;
            cv.u[0] = pack_bf2(w0.x, w0.y);
            cv.u[1] = pack_bf2(w0.z, w0.w);
            cv.u[2] = pack_bf2(w1.x, w1.y);
            cv.u[3] = pack_bf2(w1.z, w1.w);
            bf[kb][ct] = cv.s;
        }

    unsigned short* dstp = half ? Qb : Pb;
    const int ntiles = (N + 15) >> 4;
    const int stride = gridDim.x * 2;  // waves per half
    for (int t = gw >> 1; t < ntiles; t += stride) {
        const int r0 = t << 4;
        int rr = r0 + m;
        if (rr >= N) rr = N - 1;
        floatx4 acc[4];
#pragma unroll
        for (int ct = 0; ct < 4; ++ct) acc[ct] = (floatx4){0.f, 0.f, 0.f, 0.f};

#pragma unroll
        for (int kb = 0; kb < KB; ++kb) {
            short8 a;
            if (AF32) {
                const float* xp = (const float*)Xv + (size_t)rr * K + kb * 32 + q * 8;
                float4 x0 = *(const float4*)xp;
                float4 x1 = *(const float4*)(xp + 4);
                union { unsigned u[4]; short8 s; } cv;
                cv.u[0] = pack_bf2(x0.x, x0.y);
                cv.u[1] = pack_bf2(x0.z, x0.w);
                cv.u[2] = pack_bf2(x1.x, x1.y);
                cv.u[3] = pack_bf2(x1.z, x1.w);
                a = cv.s;
            } else {
                a = *(const short8*)((const unsigned short*)Xv + (size_t)rr * K + kb * 32 + q * 8);
            }
#pragma unroll
            for (int ct = 0; ct < 4; ++ct)
                acc[ct] = __builtin_amdgcn_mfma_f32_16x16x32_bf16(a, bf[kb][ct], acc[ct], 0, 0, 0);
        }

        // C/D: col = ct*16 + m, row = r0 + q*4 + i
#pragma unroll
        for (int i = 0; i < 4; ++i) {
            int row = r0 + q * 4 + i;
            if (row < N) {
#pragma unroll
                for (int ct = 0; ct < 4; ++ct)
                    dstp[(size_t)row * HID + ct * 16 + m] = f2bf(acc[ct][i]);
            }
        }
    }
}

// ------- aggregation: H = relu(mean_{s in N(n)} P[s] + bias + Q[n]) -------
// 8 nodes per wave (8 lanes/node), lane = uint4 = 8 bf16 channels.
// Q (root path) is bf16: two uint2 reads per lane.

__global__ __launch_bounds__(256)
void k_agg(const uint4* __restrict__ P8, const uint2* __restrict__ Qb4,
           const float4* __restrict__ bias4, const int* __restrict__ offs,
           const int* __restrict__ deg, const int* __restrict__ sorted,
           uint4* __restrict__ H8, int N) {
    int node = blockIdx.x * 32 + (threadIdx.x >> 3);
    int c8 = threadIdx.x & 7;
    if (node >= N) return;
    int off = offs[node];
    int c = deg[node];
    float a[8];
#pragma unroll
    for (int j = 0; j < 8; ++j) a[j] = 0.f;
    int i = 0;
    for (; i + 1 < c; i += 2) {
        int s0 = sorted[off + i];
        int s1 = sorted[off + i + 1];
        uint4 u0 = P8[(size_t)s0 * 8 + c8];
        uint4 u1 = P8[(size_t)s1 * 8 + c8];
        acc8(a, u0);
        acc8(a, u1);
    }
    if (i < c) acc8(a, P8[(size_t)sorted[off + i] * 8 + c8]);

    float inv = 1.0f / (float)(c > 0 ? c : 1);
    float4 b0 = bias4[c8 * 2], b1 = bias4[c8 * 2 + 1];
    uint2 q0 = Qb4[(size_t)node * 16 + c8 * 2];
    uint2 q1 = Qb4[(size_t)node * 16 + c8 * 2 + 1];
    float v0 = a[0] * inv + b0.x + bf2f((unsigned short)q0.x);
    float v1 = a[1] * inv + b0.y + bf2f((unsigned short)(q0.x >> 16));
    float v2 = a[2] * inv + b0.z + bf2f((unsigned short)q0.y);
    float v3 = a[3] * inv + b0.w + bf2f((unsigned short)(q0.y >> 16));
    float v4 = a[4] * inv + b1.x + bf2f((unsigned short)q1.x);
    float v5 = a[5] * inv + b1.y + bf2f((unsigned short)(q1.x >> 16));
    float v6 = a[6] * inv + b1.z + bf2f((unsigned short)q1.y);
    float v7 = a[7] * inv + b1.w + bf2f((unsigned short)(q1.y >> 16));
    v0 = fmaxf(v0, 0.f); v1 = fmaxf(v1, 0.f); v2 = fmaxf(v2, 0.f); v3 = fmaxf(v3, 0.f);
    v4 = fmaxf(v4, 0.f); v5 = fmaxf(v5, 0.f); v6 = fmaxf(v6, 0.f); v7 = fmaxf(v7, 0.f);
    uint4 hp;
    hp.x = (unsigned)f2bf(v0) | ((unsigned)f2bf(v1) << 16);
    hp.y = (unsigned)f2bf(v2) | ((unsigned)f2bf(v3) << 16);
    hp.z = (unsigned)f2bf(v4) | ((unsigned)f2bf(v5) << 16);
    hp.w = (unsigned)f2bf(v6) | ((unsigned)f2bf(v7) << 16);
    H8[(size_t)node * 8 + c8] = hp;
}

// ---------------- query: out[q] = sigmoid(sum_c Z[s][c]*Z[d][c]) ----------------
// 8 queries per wave (8 lanes each), uint4 bf16x8 loads.

__global__ __launch_bounds__(256)
void k_query(const uint4* __restrict__ Z8, const int* __restrict__ src,
             const int* __restrict__ dst, float* __restrict__ out, int Q) {
    int qi = blockIdx.x * 32 + (threadIdx.x >> 3);
    int c8 = threadIdx.x & 7;
    if (qi >= Q) return;
    int s = src[qi];
    int d = dst[qi];
    uint4 us = Z8[(size_t)s * 8 + c8];
    uint4 ud = Z8[(size_t)d * 8 + c8];
    float v =
        bf2f((unsigned short)us.x) * bf2f((unsigned short)ud.x) +
        bf2f((unsigned short)(us.x >> 16)) * bf2f((unsigned short)(ud.x >> 16)) +
        bf2f((unsigned short)us.y) * bf2f((unsigned short)ud.y) +
        bf2f((unsigned short)(us.y >> 16)) * bf2f((unsigned short)(ud.y >> 16)) +
        bf2f((unsigned short)us.z) * bf2f((unsigned short)ud.z) +
        bf2f((unsigned short)(us.z >> 16)) * bf2f((unsigned short)(ud.z >> 16)) +
        bf2f((unsigned short)us.w) * bf2f((unsigned short)ud.w) +
        bf2f((unsigned short)(us.w >> 16)) * bf2f((unsigned short)(ud.w >> 16));
#pragma unroll
    for (int mres = 4; mres > 0; mres >>= 1) v += __shfl_xor(v, mres, 64);
    if (c8 == 0) out[qi] = 1.0f / (1.0f + __expf(-v));
}

// ---------------- launch ----------------

extern "C" void kernel_launch(void* const* d_in, const int* in_sizes, int n_in,
                              void* d_out, int out_size, void* d_ws, size_t ws_size,
                              hipStream_t stream) {
    const float* x    = (const float*)d_in[0];
    const int*   ei   = (const int*)d_in[1];
    const int*   qsrc = (const int*)d_in[2];
    const int*   qdst = (const int*)d_in[3];
    const float* Wl1  = (const float*)d_in[4];
    const float* bl1  = (const float*)d_in[5];
    const float* Wr1  = (const float*)d_in[6];
    const float* Wl2  = (const float*)d_in[7];
    const float* bl2  = (const float*)d_in[8];
    const float* Wr2  = (const float*)d_in[9];
    float* out = (float*)d_out;

    const int N = in_sizes[0] / 128;  // IN_CH = 128
    const int E = in_sizes[1] / 2;
    const int Q = in_sizes[2];

    const int* esrc = ei;
    const int* edst = ei + E;

    // workspace layout (no aliasing; ws is 256 MiB)
    unsigned short* Pb = (unsigned short*)d_ws;         // N x 64 bf16 messages
    unsigned short* Qb = Pb + (size_t)N * HID;          // N x 64 bf16 root
    unsigned short* Hb = Qb + (size_t)N * HID;          // N x 64 bf16 h
    unsigned short* Zb = Hb + (size_t)N * HID;          // N x 64 bf16 z
    int* deg_c  = (int*)(Zb + (size_t)N * HID);         // N
    int* offs   = deg_c + N;                            // N
    int* total  = offs + N;                             // NB_MAX
    int* base   = total + NB_MAX;                       // NB_MAX
    int* sorted = base + NB_MAX;                        // E
    int* cnt    = sorted + E;                           // NB*G_BLK
    int* ebuf   = cnt + (size_t)NB_MAX * G_BLK;         // E

    const int NB = (N + 255) >> 8;            // buckets of 256 nodes (<= NB_MAX)
    const int CH = (E + G_BLK - 1) / G_BLK;   // edges per bucket-pass block
    const int gG = 640;                       // grid-stride MFMA gemm
    const int gA = (N + 31) / 32;             // 8 nodes/wave, 4 waves/block
    const int gQ = (Q + 31) / 32;

    // CSR build: zero global atomics
    k_bhist<<<G_BLK, 256, 0, stream>>>(edst, cnt, E, NB, CH);
    k_bscan1<<<(NB + 3) / 4, 256, 0, stream>>>(cnt, total, NB);
    k_bscan2<<<1, 512, 0, stream>>>(total, base, NB);
    k_bscatter<<<G_BLK, 256, 0, stream>>>(esrc, edst, cnt, base, ebuf, E, NB, CH);
    k_bfinal<<<NB, 256, 0, stream>>>(ebuf, total, base, sorted, deg_c, offs, N);

    // layer 1: Pb = bf16(x@Wl1^T), Qb = bf16(x@Wr1^T); Hb = bf16(relu(mean+b+Qb))
    gemm_mfma<128, true><<<gG, 256, 0, stream>>>(x, Wl1, Wr1, Pb, Qb, N);
    k_agg<<<gA, 256, 0, stream>>>((const uint4*)Pb, (const uint2*)Qb,
                                  (const float4*)bl1, offs, deg_c, sorted,
                                  (uint4*)Hb, N);

    // layer 2: Pb = bf16(Hb@Wl2^T), Qb = bf16(Hb@Wr2^T); Zb = bf16(relu(mean+b+Qb))
    gemm_mfma<64, false><<<gG, 256, 0, stream>>>(Hb, Wl2, Wr2, Pb, Qb, N);
    k_agg<<<gA, 256, 0, stream>>>((const uint4*)Pb, (const uint2*)Qb,
                                  (const float4*)bl2, offs, deg_c, sorted,
                                  (uint4*)Zb, N);

    // queries
    k_query<<<gQ, 256, 0, stream>>>((const uint4*)Zb, qsrc, qdst, out, Q);
}

// Round 12
// 255.848 us; speedup vs baseline: 1.0915x; 1.0321x over previous
//
#include <hip/hip_runtime.h>
#include <hip/hip_bf16.h>
#include <math.h>

// ---------------------------------------------------------------------------
// GNN link predictor: 2-layer GraphSAGE (mean agg) + dot-product + sigmoid.
//  - transform-then-aggregate (mean is linear) -> aggregate in 64-dim space
//  - GEMMs on MFMA (16x16x32 bf16, fp32 accum), W read f32 + packed to
//    register-resident bf16 B-frags in-kernel (no cast kernel)
//  - CSR build: 2-level LDS counting sort (bucket = dst>>8), ZERO global
//    atomics (R6/R7: returning device atomics = 24.6G/s HW wall).
//    G_BLK=512 (R9 proven; R11's 1024 doubled cnt traffic, regressed).
//  - root path Q stored bf16
//  - R12: gather kernels use v_cvt_pk_f32_bf16 (__bfloat1622float2) +
//    float2 accumulators (v_pk_add_f32) — halves VALU ops/uint4; k_agg
//    unrolled 4 neighbors (4 uint4 in flight/lane).
// ---------------------------------------------------------------------------

#define HID 64
#define G_BLK 512   // blocks in bucket passes A/C
#define NB_MAX 512  // max buckets of 256 nodes (N <= 131072)

typedef __attribute__((ext_vector_type(8))) short short8;   // 8 bf16 (4 VGPR)
typedef __attribute__((ext_vector_type(4))) float floatx4;  // MFMA acc

__device__ __forceinline__ unsigned short f2bf(float f) {
    union { float f; unsigned u; } v; v.f = f;
    unsigned r = v.u + 0x7FFF + ((v.u >> 16) & 1);  // round-to-nearest-even
    return (unsigned short)(r >> 16);
}
__device__ __forceinline__ float bf2f(unsigned short u) {
    union { unsigned u; float f; } v; v.u = ((unsigned)u) << 16;
    return v.f;
}
__device__ __forceinline__ unsigned pack_bf2(float a, float b) {
    union { __hip_bfloat162 h; unsigned u; } cv;
    cv.h = __float22bfloat162_rn(make_float2(a, b));  // v_cvt_pk_bf16_f32
    return cv.u;
}
__device__ __forceinline__ float2 bfx2(unsigned u) {  // v_cvt_pk_f32_bf16
    union { unsigned u; __hip_bfloat162 h; } cv; cv.u = u;
    return __bfloat1622float2(cv.h);
}
// accumulate one bf16x8 row (uint4) into 4 float2 accumulators
__device__ __forceinline__ void accp(float2* a, uint4 u) {
    float2 f0 = bfx2(u.x), f1 = bfx2(u.y), f2 = bfx2(u.z), f3 = bfx2(u.w);
    a[0].x += f0.x; a[0].y += f0.y;
    a[1].x += f1.x; a[1].y += f1.y;
    a[2].x += f2.x; a[2].y += f2.y;
    a[3].x += f3.x; a[3].y += f3.y;
}

// ---------------- CSR build: 2-level LDS counting sort ----------------

// Pass A: per-block LDS histogram over buckets (dst>>8). cnt[k*G_BLK + b].
__global__ __launch_bounds__(256)
void k_bhist(const int* __restrict__ edst, int* __restrict__ cnt,
             int E, int NB, int CH) {
    __shared__ int lh[NB_MAX];
    const int b = blockIdx.x;
    for (int i = threadIdx.x; i < NB; i += 256) lh[i] = 0;
    __syncthreads();
    const int e0 = b * CH;
    const int e1 = min(E, e0 + CH);
    for (int e = e0 + threadIdx.x; e < e1; e += 256)
        atomicAdd(&lh[edst[e] >> 8], 1);  // LDS atomic
    __syncthreads();
    for (int k = threadIdx.x; k < NB; k += 256)
        cnt[(size_t)k * G_BLK + b] = lh[k];
}

// Pass B1: per-bucket exclusive scan over the G_BLK block counts (wave/bucket).
__global__ __launch_bounds__(256)
void k_bscan1(int* __restrict__ cnt, int* __restrict__ total, int NB) {
    int k = blockIdx.x * 4 + (threadIdx.x >> 6);
    int lane = threadIdx.x & 63;
    if (k >= NB) return;
    int* row = cnt + (size_t)k * G_BLK;
    const int base = lane * 8;  // 8 consecutive blocks per lane
    int v[8];
#pragma unroll
    for (int j = 0; j < 8; ++j) v[j] = row[base + j];
    int s = 0;
#pragma unroll
    for (int j = 0; j < 8; ++j) s += v[j];
    int inc = s;
#pragma unroll
    for (int off = 1; off < 64; off <<= 1) {
        int o = __shfl_up(inc, off, 64);
        if (lane >= off) inc += o;
    }
    int run = inc - s;  // exclusive prefix of this lane's chunk
#pragma unroll
    for (int j = 0; j < 8; ++j) { int t = v[j]; row[base + j] = run; run += t; }
    if (lane == 63) total[k] = run;
}

// Pass B2: exclusive scan of bucket totals -> base. One block, 512 threads.
__global__ __launch_bounds__(512)
void k_bscan2(const int* __restrict__ total, int* __restrict__ base, int NB) {
    __shared__ int lds[512];
    int t = threadIdx.x;
    int v = (t < NB) ? total[t] : 0;
    lds[t] = v;
    __syncthreads();
    for (int off = 1; off < 512; off <<= 1) {
        int x = (t >= off) ? lds[t - off] : 0;
        __syncthreads();
        lds[t] += x;
        __syncthreads();
    }
    if (t < NB) base[t] = lds[t] - v;
}

// Pass C: scatter edges into bucket segments via LDS cursors (no global atomics).
// payload = (dst&255)<<24 | src  (src < 2^24).
__global__ __launch_bounds__(256)
void k_bscatter(const int* __restrict__ esrc, const int* __restrict__ edst,
                const int* __restrict__ cnt, const int* __restrict__ base,
                int* __restrict__ ebuf, int E, int NB, int CH) {
    __shared__ int cur[NB_MAX];
    const int b = blockIdx.x;
    for (int k = threadIdx.x; k < NB; k += 256)
        cur[k] = base[k] + cnt[(size_t)k * G_BLK + b];
    __syncthreads();
    const int e0 = b * CH;
    const int e1 = min(E, e0 + CH);
    for (int e = e0 + threadIdx.x; e < e1; e += 256) {
        int d = edst[e];
        int slot = atomicAdd(&cur[d >> 8], 1);  // LDS atomic
        ebuf[slot] = ((d & 255) << 24) | esrc[e];
    }
}

// Pass D: per-bucket local counting sort -> sorted[], deg[], offs[].
__global__ __launch_bounds__(256)
void k_bfinal(const int* __restrict__ ebuf, const int* __restrict__ total,
              const int* __restrict__ base, int* __restrict__ sorted,
              int* __restrict__ deg, int* __restrict__ offs, int N) {
    __shared__ int h[256], loc[256], cur[256], sc[256];
    const int k = blockIdx.x;
    const int t = threadIdx.x;
    const int nk = total[k];
    const int bs = base[k];
    h[t] = 0;
    __syncthreads();
    for (int i = bs + t; i < bs + nk; i += 256)
        atomicAdd(&h[(ebuf[i] >> 24) & 255], 1);
    __syncthreads();
    int v = h[t];
    sc[t] = v;
    __syncthreads();
    for (int off = 1; off < 256; off <<= 1) {
        int x = (t >= off) ? sc[t - off] : 0;
        __syncthreads();
        sc[t] += x;
        __syncthreads();
    }
    loc[t] = sc[t] - v;
    cur[t] = sc[t] - v;
    __syncthreads();
    for (int i = bs + t; i < bs + nk; i += 256) {
        int pk = ebuf[i];
        int j = (pk >> 24) & 255;
        int r = atomicAdd(&cur[j], 1);  // LDS atomic
        sorted[bs + r] = pk & 0xFFFFFF;
    }
    int node = (k << 8) + t;
    if (node < N) {
        deg[node] = v;
        offs[node] = bs + loc[t];
    }
}

// ---------------- MFMA dual GEMM: [P|Q] = A @ [Wl;Wr]^T ----------------
// Wave computes 16 rows x 64 cols (half=0 -> P, half=1 -> Q), both bf16 out.
// B-frags: read f32 W rows once per wave, pack to bf16 registers.
// A is f32 (layer 1, cvt in-flight) or bf16 (layer 2).

template <int K, bool AF32>
__global__ __launch_bounds__(256, 2)
void gemm_mfma(const void* __restrict__ Xv, const float* __restrict__ Wl,
               const float* __restrict__ Wr, unsigned short* __restrict__ Pb,
               unsigned short* __restrict__ Qb, int N) {
    const int lane = threadIdx.x & 63;
    const int m = lane & 15;        // row (A) / col (B) within tile
    const int q = lane >> 4;        // k-quad
    const int gw = blockIdx.x * 4 + (threadIdx.x >> 6);
    const int half = gw & 1;        // 0 -> P, 1 -> Q
    constexpr int KB = K / 32;

    const float* Wh = half ? Wr : Wl;
    short8 bf[KB][4];
#pragma unroll
    for (int kb = 0; kb < KB; ++kb)
#pragma unroll
        for (int ct = 0; ct < 4; ++ct) {
            int c = ct * 16 + m;
            const float* wp = Wh + (size_t)c * K + kb * 32 + q * 8;
            float4 w0 = *(const float4*)wp;
            float4 w1 = *(const float4*)(wp + 4);
            union { unsigned u[4]; short8 s; } cv;
            cv.u[0] = pack_bf2(w0.x, w0.y);
            cv.u[1] = pack_bf2(w0.z, w0.w);
            cv.u[2] = pack_bf2(w1.x, w1.y);
            cv.u[3] = pack_bf2(w1.z, w1.w);
            bf[kb][ct] = cv.s;
        }

    unsigned short* dstp = half ? Qb : Pb;
    const int ntiles = (N + 15) >> 4;
    const int stride = gridDim.x * 2;  // waves per half
    for (int t = gw >> 1; t < ntiles; t += stride) {
        const int r0 = t << 4;
        int rr = r0 + m;
        if (rr >= N) rr = N - 1;
        floatx4 acc[4];
#pragma unroll
        for (int ct = 0; ct < 4; ++ct) acc[ct] = (floatx4){0.f, 0.f, 0.f, 0.f};

#pragma unroll
        for (int kb = 0; kb < KB; ++kb) {
            short8 a;
            if (AF32) {
                const float* xp = (const float*)Xv + (size_t)rr * K + kb * 32 + q * 8;
                float4 x0 = *(const float4*)xp;
                float4 x1 = *(const float4*)(xp + 4);
                union { unsigned u[4]; short8 s; } cv;
                cv.u[0] = pack_bf2(x0.x, x0.y);
                cv.u[1] = pack_bf2(x0.z, x0.w);
                cv.u[2] = pack_bf2(x1.x, x1.y);
                cv.u[3] = pack_bf2(x1.z, x1.w);
                a = cv.s;
            } else {
                a = *(const short8*)((const unsigned short*)Xv + (size_t)rr * K + kb * 32 + q * 8);
            }
#pragma unroll
            for (int ct = 0; ct < 4; ++ct)
                acc[ct] = __builtin_amdgcn_mfma_f32_16x16x32_bf16(a, bf[kb][ct], acc[ct], 0, 0, 0);
        }

        // C/D: col = ct*16 + m, row = r0 + q*4 + i
#pragma unroll
        for (int i = 0; i < 4; ++i) {
            int row = r0 + q * 4 + i;
            if (row < N) {
#pragma unroll
                for (int ct = 0; ct < 4; ++ct)
                    dstp[(size_t)row * HID + ct * 16 + m] = f2bf(acc[ct][i]);
            }
        }
    }
}

// ------- aggregation: H = relu(mean_{s in N(n)} P[s] + bias + Q[n]) -------
// 8 nodes per wave (8 lanes/node), lane = uint4 = 8 bf16 channels.
// Packed cvt (v_cvt_pk_f32_bf16) + float2 accumulators; 4-deep unroll.

__global__ __launch_bounds__(256)
void k_agg(const uint4* __restrict__ P8, const uint2* __restrict__ Qb4,
           const float4* __restrict__ bias4, const int* __restrict__ offs,
           const int* __restrict__ deg, const int* __restrict__ sorted,
           uint4* __restrict__ H8, int N) {
    int node = blockIdx.x * 32 + (threadIdx.x >> 3);
    int c8 = threadIdx.x & 7;
    if (node >= N) return;
    int off = offs[node];
    int c = deg[node];
    float2 a[4];
#pragma unroll
    for (int j = 0; j < 4; ++j) a[j] = make_float2(0.f, 0.f);
    int i = 0;
    for (; i + 3 < c; i += 4) {
        int s0 = sorted[off + i];
        int s1 = sorted[off + i + 1];
        int s2 = sorted[off + i + 2];
        int s3 = sorted[off + i + 3];
        uint4 u0 = P8[(size_t)s0 * 8 + c8];
        uint4 u1 = P8[(size_t)s1 * 8 + c8];
        uint4 u2 = P8[(size_t)s2 * 8 + c8];
        uint4 u3 = P8[(size_t)s3 * 8 + c8];
        accp(a, u0); accp(a, u1); accp(a, u2); accp(a, u3);
    }
    for (; i < c; ++i) accp(a, P8[(size_t)sorted[off + i] * 8 + c8]);

    float inv = 1.0f / (float)(c > 0 ? c : 1);
    float4 b0 = bias4[c8 * 2], b1 = bias4[c8 * 2 + 1];
    uint2 q0 = Qb4[(size_t)node * 16 + c8 * 2];
    uint2 q1 = Qb4[(size_t)node * 16 + c8 * 2 + 1];
    float2 r0 = bfx2(q0.x), r1 = bfx2(q0.y), r2 = bfx2(q1.x), r3 = bfx2(q1.y);
    float v0 = a[0].x * inv + b0.x + r0.x;
    float v1 = a[0].y * inv + b0.y + r0.y;
    float v2 = a[1].x * inv + b0.z + r1.x;
    float v3 = a[1].y * inv + b0.w + r1.y;
    float v4 = a[2].x * inv + b1.x + r2.x;
    float v5 = a[2].y * inv + b1.y + r2.y;
    float v6 = a[3].x * inv + b1.z + r3.x;
    float v7 = a[3].y * inv + b1.w + r3.y;
    v0 = fmaxf(v0, 0.f); v1 = fmaxf(v1, 0.f); v2 = fmaxf(v2, 0.f); v3 = fmaxf(v3, 0.f);
    v4 = fmaxf(v4, 0.f); v5 = fmaxf(v5, 0.f); v6 = fmaxf(v6, 0.f); v7 = fmaxf(v7, 0.f);
    uint4 hp;
    hp.x = pack_bf2(v0, v1);
    hp.y = pack_bf2(v2, v3);
    hp.z = pack_bf2(v4, v5);
    hp.w = pack_bf2(v6, v7);
    H8[(size_t)node * 8 + c8] = hp;
}

// ---------------- query: out[q] = sigmoid(sum_c Z[s][c]*Z[d][c]) ----------------
// 8 queries per wave (8 lanes each), uint4 bf16x8 loads, packed cvt + fma.

__global__ __launch_bounds__(256)
void k_query(const uint4* __restrict__ Z8, const int* __restrict__ src,
             const int* __restrict__ dst, float* __restrict__ out, int Q) {
    int qi = blockIdx.x * 32 + (threadIdx.x >> 3);
    int c8 = threadIdx.x & 7;
    if (qi >= Q) return;
    int s = src[qi];
    int d = dst[qi];
    uint4 us = Z8[(size_t)s * 8 + c8];
    uint4 ud = Z8[(size_t)d * 8 + c8];
    float2 p0 = bfx2(us.x), p1 = bfx2(us.y), p2 = bfx2(us.z), p3 = bfx2(us.w);
    float2 t0 = bfx2(ud.x), t1 = bfx2(ud.y), t2 = bfx2(ud.z), t3 = bfx2(ud.w);
    float2 acc2 = make_float2(p0.x * t0.x, p0.y * t0.y);
    acc2.x = fmaf(p1.x, t1.x, acc2.x); acc2.y = fmaf(p1.y, t1.y, acc2.y);
    acc2.x = fmaf(p2.x, t2.x, acc2.x); acc2.y = fmaf(p2.y, t2.y, acc2.y);
    acc2.x = fmaf(p3.x, t3.x, acc2.x); acc2.y = fmaf(p3.y, t3.y, acc2.y);
    float v = acc2.x + acc2.y;
#pragma unroll
    for (int mres = 4; mres > 0; mres >>= 1) v += __shfl_xor(v, mres, 64);
    if (c8 == 0) out[qi] = 1.0f / (1.0f + __expf(-v));
}

// ---------------- launch ----------------

extern "C" void kernel_launch(void* const* d_in, const int* in_sizes, int n_in,
                              void* d_out, int out_size, void* d_ws, size_t ws_size,
                              hipStream_t stream) {
    const float* x    = (const float*)d_in[0];
    const int*   ei   = (const int*)d_in[1];
    const int*   qsrc = (const int*)d_in[2];
    const int*   qdst = (const int*)d_in[3];
    const float* Wl1  = (const float*)d_in[4];
    const float* bl1  = (const float*)d_in[5];
    const float* Wr1  = (const float*)d_in[6];
    const float* Wl2  = (const float*)d_in[7];
    const float* bl2  = (const float*)d_in[8];
    const float* Wr2  = (const float*)d_in[9];
    float* out = (float*)d_out;

    const int N = in_sizes[0] / 128;  // IN_CH = 128
    const int E = in_sizes[1] / 2;
    const int Q = in_sizes[2];

    const int* esrc = ei;
    const int* edst = ei + E;

    // workspace layout (no aliasing; ws is plenty)
    unsigned short* Pb = (unsigned short*)d_ws;         // N x 64 bf16 messages
    unsigned short* Qb = Pb + (size_t)N * HID;          // N x 64 bf16 root
    unsigned short* Hb = Qb + (size_t)N * HID;          // N x 64 bf16 h
    unsigned short* Zb = Hb + (size_t)N * HID;          // N x 64 bf16 z
    int* deg_c  = (int*)(Zb + (size_t)N * HID);         // N
    int* offs   = deg_c + N;                            // N
    int* total  = offs + N;                             // NB_MAX
    int* base   = total + NB_MAX;                       // NB_MAX
    int* sorted = base + NB_MAX;                        // E
    int* cnt    = sorted + E;                           // NB_MAX*G_BLK
    int* ebuf   = cnt + (size_t)NB_MAX * G_BLK;         // E

    const int NB = (N + 255) >> 8;            // buckets of 256 nodes (<= NB_MAX)
    const int CH = (E + G_BLK - 1) / G_BLK;   // edges per bucket-pass block
    const int gG = 640;                       // grid-stride MFMA gemm
    const int gA = (N + 31) / 32;             // 8 nodes/wave, 4 waves/block
    const int gQ = (Q + 31) / 32;

    // CSR build: zero global atomics
    k_bhist<<<G_BLK, 256, 0, stream>>>(edst, cnt, E, NB, CH);
    k_bscan1<<<(NB + 3) / 4, 256, 0, stream>>>(cnt, total, NB);
    k_bscan2<<<1, 512, 0, stream>>>(total, base, NB);
    k_bscatter<<<G_BLK, 256, 0, stream>>>(esrc, edst, cnt, base, ebuf, E, NB, CH);
    k_bfinal<<<NB, 256, 0, stream>>>(ebuf, total, base, sorted, deg_c, offs, N);

    // layer 1: Pb = bf16(x@Wl1^T), Qb = bf16(x@Wr1^T); Hb = bf16(relu(mean+b+Qb))
    gemm_mfma<128, true><<<gG, 256, 0, stream>>>(x, Wl1, Wr1, Pb, Qb, N);
    k_agg<<<gA, 256, 0, stream>>>((const uint4*)Pb, (const uint2*)Qb,
                                  (const float4*)bl1, offs, deg_c, sorted,
                                  (uint4*)Hb, N);

    // layer 2: Pb = bf16(Hb@Wl2^T), Qb = bf16(Hb@Wr2^T); Zb = bf16(relu(mean+b+Qb))
    gemm_mfma<64, false><<<gG, 256, 0, stream>>>(Hb, Wl2, Wr2, Pb, Qb, N);
    k_agg<<<gA, 256, 0, stream>>>((const uint4*)Pb, (const uint2*)Qb,
                                  (const float4*)bl2, offs, deg_c, sorted,
                                  (uint4*)Zb, N);

    // queries
    k_query<<<gQ, 256, 0, stream>>>((const uint4*)Zb, qsrc, qdst, out, Q);
}